// Round 8
// baseline (544.969 us; speedup 1.0000x reference)
//
#include <hip/hip_runtime.h>
#include <hip/hip_bf16.h>

// B=8, S=4096, E=512, QKV=512, H=8, D=64, M=B*S=32768
// R11 pipeline (4 launches):
//   prep:      x fp32 -> bf16 xb + W transposes -> wt + zero ksg/kvg
//   gemm_qkv:  q = act(x@Wq+b) row-major; k,v stored ONLY TRANSPOSED
//              kT/vT[bh][d|m][4096] bf16 (k act'd), XCD-swizzled grid.
//              k-blocks also atomically accumulate ksum (fp32) into ksg.
//   kv:        MFMA GEMM over s (sc=8 x 512), 2-phase dbuf, counted vmcnt(4);
//              epilogue fp32 atomicAdd into kvg[bh][m][d].
//   fused_out: per 128x256 out block (2 ntiles): 34.5KB LDS (sQ+sO1 only),
//              4 blocks/CU. B-operands (kvg, Wo) read DIRECT from L2 as MFMA
//              fragments (no LDS staging). 3 barriers/h; next-h sQ stage
//              overlaps out-MFMA.
// Scratch:
//   d_out[0,32M):  vT (dead after kv), then final out rows
//   d_out[32,64M): xb (dead after gemm_qkv) -> final out rows
//   ws: qb[0,32M) kT[32,64M) wt[64,66M) kvg[66,67M) ksg

typedef __bf16 bf16x8 __attribute__((ext_vector_type(8)));
typedef float  f32x4  __attribute__((ext_vector_type(4)));

__device__ __forceinline__ unsigned short f2b(float f) {
    unsigned int u = __builtin_bit_cast(unsigned int, f);
    unsigned int r = (u + 0x7FFFu + ((u >> 16) & 1u)) >> 16;
    return (unsigned short)r;
}
__device__ __forceinline__ void load_lds16(const unsigned short* g, unsigned short* l) {
    __builtin_amdgcn_global_load_lds(
        (const __attribute__((address_space(1))) void*)g,
        (__attribute__((address_space(3))) void*)l, 16, 0, 0);
}

// ---------------- prep: W transpose (blocks 0..255) + x cvt (blocks 256..) ---
__global__ void prep_kernel(const float* __restrict__ x,
                            const float* __restrict__ w0, const float* __restrict__ w1,
                            const float* __restrict__ w2, const float* __restrict__ w3,
                            unsigned short* __restrict__ xb, unsigned short* __restrict__ wt,
                            float* __restrict__ ksg, float* __restrict__ kvg) {
    __shared__ float tile[64][65];
    int t = threadIdx.x;
    if (blockIdx.x >= 256) {
        int i = (blockIdx.x - 256) * 256 + t;   // < 4194304
        float4 v = ((const float4*)x)[i];
        ushort4 o;
        o.x = f2b(v.x); o.y = f2b(v.y); o.z = f2b(v.z); o.w = f2b(v.w);
        ((ushort4*)xb)[i] = o;
        return;
    }
    int idx = blockIdx.x;
    if (idx < 16) ksg[idx * 256 + t] = 0.f;                 // zero ksum (4096 f32)
    ((float4*)kvg)[idx * 256 + t] = (float4){0.f, 0.f, 0.f, 0.f};  // zero kvg (1 MB)
    int bz = idx >> 6, by = (idx >> 3) & 7, bx = idx & 7;
    const float* src = (bz == 0) ? w0 : (bz == 1) ? w1 : (bz == 2) ? w2 : w3;
    unsigned short* dst = wt + (size_t)bz * 512 * 512;
    int rb = by * 64, cb = bx * 64;
    #pragma unroll
    for (int i = 0; i < 16; i++) {
        int c = t + i * 256; int r = c >> 6, cc = c & 63;
        tile[r][cc] = src[(rb + r) * 512 + cb + cc];
    }
    __syncthreads();
    #pragma unroll
    for (int i = 0; i < 16; i++) {
        int c = t + i * 256; int r = c >> 6, cc = c & 63;
        dst[(cb + r) * 512 + rb + cc] = f2b(tile[cc][r]);   // Wt[n][k]=W[k][n]
    }
}

// ---------------- gemm_qkv: 128x128 MFMA, q row-major / k,v transposed -------
// grid: 3072 1-D, XCD-swizzled: all 12 (tensor,ntile) blocks of one mtile get
// equal blockIdx%8 -> same XCD -> A-tile L2 hit.
// k-blocks (tensor==1) also accumulate fp32 column sums -> atomicAdd ksg.
__global__ __launch_bounds__(256, 4) void gemm_qkv_kernel(
        const unsigned short* __restrict__ xb, const unsigned short* __restrict__ wt,
        const float* __restrict__ bq, const float* __restrict__ bk, const float* __restrict__ bv,
        unsigned short* __restrict__ qb, unsigned short* __restrict__ kT,
        unsigned short* __restrict__ vT, float* __restrict__ ksg) {
    int g = blockIdx.x;
    int xcd = g & 7, slot = g >> 3;            // slot 0..383
    int mtile = xcd * 32 + slot / 12;
    int tn = slot % 12;
    int tensor = tn >> 2, ntile = tn & 3;
    const unsigned short* Bt = wt + (size_t)tensor * 512 * 512;
    const float* bias = tensor == 0 ? bq : tensor == 1 ? bk : bv;
    bool act = tensor < 2;

    __shared__ __align__(16) unsigned short sA[128 * 64];
    __shared__ __align__(16) unsigned short sB[128 * 64];
    const int tid  = threadIdx.x;
    const int wave = tid >> 6, lane = tid & 63;
    const int wm = wave >> 1, wn = wave & 1;
    const int quad = lane >> 4, l16 = lane & 15;
    const int mbase = mtile * 128, nbase = ntile * 128;
    const int rsub = lane >> 3;
    const int coff = (((lane & 7) ^ rsub) << 3);

    f32x4 acc[4][4];
    #pragma unroll
    for (int i = 0; i < 4; i++)
        #pragma unroll
        for (int j = 0; j < 4; j++) acc[i][j] = (f32x4){0.f, 0.f, 0.f, 0.f};

    for (int kb = 0; kb < 512; kb += 64) {
        #pragma unroll
        for (int t = 0; t < 4; t++) {
            int r0 = t * 32 + wave * 8;
            load_lds16(&xb[(size_t)(mbase + r0 + rsub) * 512 + kb + coff], &sA[r0 * 64]);
            load_lds16(&Bt[(size_t)(nbase + r0 + rsub) * 512 + kb + coff], &sB[r0 * 64]);
        }
        __syncthreads();
        #pragma unroll
        for (int ko = 0; ko < 64; ko += 32) {
            bf16x8 af[4], bfr[4];
            int pg = ((quad + (ko >> 3)) ^ (l16 & 7)) << 3;
            #pragma unroll
            for (int f = 0; f < 4; f++)
                af[f] = *(const bf16x8*)&sA[(wm * 64 + f * 16 + l16) * 64 + pg];
            #pragma unroll
            for (int f = 0; f < 4; f++)
                bfr[f] = *(const bf16x8*)&sB[(wn * 64 + f * 16 + l16) * 64 + pg];
            #pragma unroll
            for (int i = 0; i < 4; i++)
                #pragma unroll
                for (int j = 0; j < 4; j++)
                    acc[i][j] = __builtin_amdgcn_mfma_f32_16x16x32_bf16(af[i], bfr[j], acc[i][j], 0, 0, 0);
        }
        __syncthreads();
    }
    // epilogue. C/D layout: col = lane&15, row = quad*4+reg (m89-verified).
    if (tensor == 0) {
        #pragma unroll
        for (int i = 0; i < 4; i++)
            #pragma unroll
            for (int j = 0; j < 4; j++) {
                int gcol = nbase + wn * 64 + j * 16 + l16;
                float bv = bias[gcol];
                #pragma unroll
                for (int r = 0; r < 4; r++) {
                    int grow = mbase + wm * 64 + i * 16 + quad * 4 + r;
                    float v = acc[i][j][r] + bv;
                    v = v > 0.f ? v + 1.f : __expf(v);
                    qb[(size_t)grow * 512 + gcol] = f2b(v);
                }
            }
    } else {
        // transposed store: T[((b*8+h)*64 + d)*4096 + s], 4 consecutive s
        // (the 4 acc regs = rows quad*4+0..3) packed into one ushort4.
        unsigned short* T = (tensor == 1) ? kT : vT;
        float csum[4] = {0.f, 0.f, 0.f, 0.f};
        #pragma unroll
        for (int i = 0; i < 4; i++)
            #pragma unroll
            for (int j = 0; j < 4; j++) {
                int gcol = nbase + wn * 64 + j * 16 + l16;   // 0..511
                int h = gcol >> 6, d = gcol & 63;
                float bv = bias[gcol];
                int grow0 = mbase + wm * 64 + i * 16 + quad * 4;
                int b = grow0 >> 12, s0 = grow0 & 4095;
                ushort4 o;
                #pragma unroll
                for (int r = 0; r < 4; r++) {
                    float v = acc[i][j][r] + bv;
                    if (act) { v = v > 0.f ? v + 1.f : __expf(v); csum[j] += v; }
                    ((unsigned short*)&o)[r] = f2b(v);
                }
                *(ushort4*)&T[(((size_t)b * 8 + h) * 64 + d) * 4096 + s0] = o;
            }
        if (act) {   // tensor==1 (k): fp32 ksum accumulation, pre-bf16-rounding
            int b = mbase >> 12;
            #pragma unroll
            for (int j = 0; j < 4; j++) {
                float s = csum[j];
                s += __shfl_xor(s, 16, 64);   // quad reduce (rows quad*4+r)
                s += __shfl_xor(s, 32, 64);
                if (quad == 0) {
                    int gcol = nbase + wn * 64 + j * 16 + l16;
                    atomicAdd(&ksg[b * 512 + gcol], s);
                }
            }
        }
    }
}

// ---------------- kv: MFMA GEMM over s, 2-phase dbuf -------------------------
// grid: x = bh(64) * sc(8); block: C[64 m][64 d] partial over 512 s.
// Stage t+1 issued before compute t; counted vmcnt(4) + raw s_barrier (no
// full drain in-loop). Epilogue: fp32 atomicAdd into kvg[bh][m*64+d].
__global__ __launch_bounds__(256, 2) void kv_kernel(
        const unsigned short* __restrict__ kT, const unsigned short* __restrict__ vT,
        float* __restrict__ kvg) {
    int bh = blockIdx.x >> 3, sc = blockIdx.x & 7;
    const int tid = threadIdx.x;
    const int wave = tid >> 6, lane = tid & 63;
    const int wm = wave >> 1, wn = wave & 1;
    const int quad = lane >> 4, l16 = lane & 15;
    const int rsub = lane >> 3;
    const int coff = (((lane & 7) ^ rsub) << 3);
    __shared__ __align__(16) unsigned short sV[2][64 * 64];
    __shared__ __align__(16) unsigned short sK[2][64 * 64];

    f32x4 acc[2][2];
    #pragma unroll
    for (int i = 0; i < 2; i++)
        #pragma unroll
        for (int j = 0; j < 2; j++) acc[i][j] = (f32x4){0.f, 0.f, 0.f, 0.f};
    size_t base = (size_t)bh * 64 * 4096 + sc * 512;

    auto stage = [&](int kb, int buf) {
        int s0 = kb * 64;
        #pragma unroll
        for (int t = 0; t < 2; t++) {
            int r0 = t * 32 + wave * 8;
            load_lds16(&vT[base + (size_t)(r0 + rsub) * 4096 + s0 + coff], &sV[buf][r0 * 64]);
            load_lds16(&kT[base + (size_t)(r0 + rsub) * 4096 + s0 + coff], &sK[buf][r0 * 64]);
        }
    };

    stage(0, 0);                               // 4 loads in flight
    for (int kb = 0; kb < 8; kb++) {           // 8 x 64 s
        int buf = kb & 1;
        if (kb < 7) {
            stage(kb + 1, buf ^ 1);            // +4 -> 8 in flight
            asm volatile("s_waitcnt vmcnt(4)" ::: "memory");   // tile kb landed
        } else {
            asm volatile("s_waitcnt vmcnt(0)" ::: "memory");
        }
        __builtin_amdgcn_sched_barrier(0);
        __builtin_amdgcn_s_barrier();
        #pragma unroll
        for (int ko = 0; ko < 64; ko += 32) {
            bf16x8 af[2], bfr[2];
            int pg = ((quad + (ko >> 3)) ^ (l16 & 7)) << 3;
            #pragma unroll
            for (int f = 0; f < 2; f++)
                af[f] = *(const bf16x8*)&sV[buf][(wm * 32 + f * 16 + l16) * 64 + pg];
            #pragma unroll
            for (int f = 0; f < 2; f++)
                bfr[f] = *(const bf16x8*)&sK[buf][(wn * 32 + f * 16 + l16) * 64 + pg];
            #pragma unroll
            for (int i = 0; i < 2; i++)
                #pragma unroll
                for (int j = 0; j < 2; j++)
                    acc[i][j] = __builtin_amdgcn_mfma_f32_16x16x32_bf16(af[i], bfr[j], acc[i][j], 0, 0, 0);
        }
        __builtin_amdgcn_s_barrier();          // protect buf from next re-stage
        __builtin_amdgcn_sched_barrier(0);
    }
    // epilogue: accumulate fp32 partial into kvg (8 sc contenders per cell)
    float* out = kvg + (size_t)bh * 4096;
    #pragma unroll
    for (int i = 0; i < 2; i++)
        #pragma unroll
        for (int j = 0; j < 2; j++)
            #pragma unroll
            for (int r = 0; r < 4; r++) {
                int m = wm * 32 + i * 16 + quad * 4 + r;
                int d = wn * 32 + j * 16 + l16;
                atomicAdd(&out[m * 64 + d], acc[i][j][r]);
            }
}

// ---------------- fused out1 + output GEMM -----------------------------------
// grid: 512 1-D, XCD-swizzled (2 np blocks of one mtile -> same XCD).
// Each block: 128 rows x 256 cols (2 ntiles); o1/z/sQ computed ONCE per block.
// LDS 34.5KB (sQ + sO1 only) -> 4 blocks/CU. kv and Wo B-fragments read
// DIRECT from global (L2-resident: kvg 1MB, wt 512KB); fragment addr
// src[row*ld + h*64 + ko + quad*8] (staging-XOR algebra cancels).
__global__ __launch_bounds__(256, 4) void fused_out_kernel(
        const unsigned short* __restrict__ qb,
        const float* __restrict__ kvg, const float* __restrict__ ksg,
        const unsigned short* __restrict__ wto, const float* __restrict__ bo,
        float* __restrict__ out) {
    int g = blockIdx.x;
    int xcd = g & 7, slot = g >> 3;            // slot 0..63
    int mtile = xcd * 32 + (slot >> 1);
    int np = slot & 1;                         // col half: np*256 .. np*256+255

    __shared__ __align__(16) unsigned short sQ[128 * 64];
    __shared__ __align__(16) unsigned short sO1[128 * 64];
    __shared__ float sKsum[512];
    __shared__ float sZ[128];
    const int tid  = threadIdx.x;
    const int wave = tid >> 6, lane = tid & 63;
    const int wm = wave >> 1, wn = wave & 1;
    const int quad = lane >> 4, l16 = lane & 15;
    const int mbase = mtile * 128, nbase = np * 256;
    const int b = mtile >> 5;
    const int rsub = lane >> 3;
    const int coff = (((lane & 7) ^ rsub) << 3);

    // stage fp32 ksum for this b (512 cols = 8 h x 64 d)
    sKsum[tid]       = ksg[b * 512 + tid];
    sKsum[tid + 256] = ksg[b * 512 + 256 + tid];

    f32x4 accm[2][4][4];
    #pragma unroll
    for (int n = 0; n < 2; n++)
        #pragma unroll
        for (int i = 0; i < 4; i++)
            #pragma unroll
            for (int j = 0; j < 4; j++) accm[n][i][j] = (f32x4){0.f, 0.f, 0.f, 0.f};

    // prologue: stage sQ for h=0
    #pragma unroll
    for (int t = 0; t < 4; t++) {
        int r0 = t * 32 + wave * 8;
        load_lds16(&qb[(size_t)(mbase + r0 + rsub) * 512 + coff], &sQ[r0 * 64]);
    }

    for (int h = 0; h < 8; h++) {
        __syncthreads();   // sQ(h) staged (vmcnt drained); sO1 free (prev out-MFMA done)
        // z = 1/(q_h . ksum_h + eps) per row, from swizzled sQ (fp32 accum).
        {
            int row = tid >> 1, half = tid & 1;
            const float* ksh = &sKsum[h * 64];
            float dsum = 0.f;
            #pragma unroll
            for (int g2 = 0; g2 < 4; g2++) {
                int G = half * 4 + g2;                       // global octet
                uint4 w = *(const uint4*)&sQ[row * 64 + ((G ^ (row & 7)) << 3)];
                const unsigned int* qp = (const unsigned int*)&w;
                #pragma unroll
                for (int u = 0; u < 4; u++) {
                    int c = G * 8 + u * 2;
                    dsum += __builtin_bit_cast(float, qp[u] << 16)        * ksh[c];
                    dsum += __builtin_bit_cast(float, qp[u] & 0xFFFF0000u) * ksh[c + 1];
                }
            }
            dsum += __shfl_xor(dsum, 1, 64);
            if (!half) sZ[row] = 1.f / (dsum + 1e-6f);
        }
        // o1 = q_h @ kv_h^T; B-fragments direct from kvg (fp32 -> bf16 pack)
        f32x4 acco[4][2];
        #pragma unroll
        for (int f = 0; f < 4; f++)
            #pragma unroll
            for (int j = 0; j < 2; j++) acco[f][j] = (f32x4){0.f, 0.f, 0.f, 0.f};
        const float* kvh = &kvg[((size_t)(b * 8 + h)) * 4096];
        #pragma unroll
        for (int ko = 0; ko < 64; ko += 32) {
            bf16x8 af[4], bfr[2];
            int pg = ((quad + (ko >> 3)) ^ (l16 & 7)) << 3;
            #pragma unroll
            for (int f = 0; f < 4; f++)
                af[f] = *(const bf16x8*)&sQ[(wm * 64 + f * 16 + l16) * 64 + pg];
            #pragma unroll
            for (int j = 0; j < 2; j++) {
                const float* kp = kvh + (wn * 32 + j * 16 + l16) * 64 + ko + quad * 8;
                float4 ka = *(const float4*)kp;
                float4 kb = *(const float4*)(kp + 4);
                uint4 pk;
                pk.x = (unsigned int)f2b(ka.x) | ((unsigned int)f2b(ka.y) << 16);
                pk.y = (unsigned int)f2b(ka.z) | ((unsigned int)f2b(ka.w) << 16);
                pk.z = (unsigned int)f2b(kb.x) | ((unsigned int)f2b(kb.y) << 16);
                pk.w = (unsigned int)f2b(kb.z) | ((unsigned int)f2b(kb.w) << 16);
                bfr[j] = __builtin_bit_cast(bf16x8, pk);
            }
            #pragma unroll
            for (int f = 0; f < 4; f++)
                #pragma unroll
                for (int j = 0; j < 2; j++)
                    acco[f][j] = __builtin_amdgcn_mfma_f32_16x16x32_bf16(af[f], bfr[j], acco[f][j], 0, 0, 0);
        }
        __syncthreads();   // sZ ready (sO1 prev reads already fenced by top barrier)
        // scale by z, write to sO1 (swizzled A-layout)
        #pragma unroll
        for (int f = 0; f < 4; f++)
            #pragma unroll
            for (int j = 0; j < 2; j++)
                #pragma unroll
                for (int r = 0; r < 4; r++) {
                    int row = wm * 64 + f * 16 + quad * 4 + r;
                    int col = wn * 32 + j * 16 + l16;
                    float v = acco[f][j][r] * sZ[row];
                    int grp = col >> 3;
                    sO1[row * 64 + ((grp ^ (row & 7)) << 3) + (col & 7)] = f2b(v);
                }
        __syncthreads();   // sO1 ready
        if (h < 7) {       // stage next-h sQ; overlaps out-MFMA below
            #pragma unroll
            for (int t = 0; t < 4; t++) {
                int r0 = t * 32 + wave * 8;
                load_lds16(&qb[(size_t)(mbase + r0 + rsub) * 512 + (h + 1) * 64 + coff], &sQ[r0 * 64]);
            }
        }
        // out-MFMA: accumulate o1_h @ Wo_h; B-fragments direct from wto (bf16)
        #pragma unroll
        for (int ko = 0; ko < 64; ko += 32) {
            bf16x8 af[4], bfr0[4], bfr1[4];
            int pg = ((quad + (ko >> 3)) ^ (l16 & 7)) << 3;
            #pragma unroll
            for (int f = 0; f < 4; f++)
                af[f] = *(const bf16x8*)&sO1[(wm * 64 + f * 16 + l16) * 64 + pg];
            #pragma unroll
            for (int f = 0; f < 4; f++) {
                bfr0[f] = *(const bf16x8*)&wto[(size_t)(nbase + wn * 64 + f * 16 + l16) * 512 + h * 64 + ko + quad * 8];
                bfr1[f] = *(const bf16x8*)&wto[(size_t)(nbase + 128 + wn * 64 + f * 16 + l16) * 512 + h * 64 + ko + quad * 8];
            }
            #pragma unroll
            for (int i = 0; i < 4; i++)
                #pragma unroll
                for (int j = 0; j < 4; j++) {
                    accm[0][i][j] = __builtin_amdgcn_mfma_f32_16x16x32_bf16(af[i], bfr0[j], accm[0][i][j], 0, 0, 0);
                    accm[1][i][j] = __builtin_amdgcn_mfma_f32_16x16x32_bf16(af[i], bfr1[j], accm[1][i][j], 0, 0, 0);
                }
        }
    }
    #pragma unroll
    for (int n = 0; n < 2; n++)
        #pragma unroll
        for (int i = 0; i < 4; i++)
            #pragma unroll
            for (int j = 0; j < 4; j++) {
                int gcol = nbase + n * 128 + wn * 64 + j * 16 + l16;
                float bvv = bo[gcol];
                #pragma unroll
                for (int r = 0; r < 4; r++) {
                    int grow = mbase + wm * 64 + i * 16 + quad * 4 + r;
                    out[(size_t)grow * 512 + gcol] = accm[n][i][j][r] + bvv;
                }
            }
}

// ---------------- launch -----------------------------------------------------
extern "C" void kernel_launch(void* const* d_in, const int* in_sizes, int n_in,
                              void* d_out, int out_size, void* d_ws, size_t ws_size,
                              hipStream_t stream) {
    const float* x  = (const float*)d_in[0];
    const float* Wq = (const float*)d_in[1];
    const float* bq = (const float*)d_in[2];
    const float* Wk = (const float*)d_in[3];
    const float* bk = (const float*)d_in[4];
    const float* Wv = (const float*)d_in[5];
    const float* bv = (const float*)d_in[6];
    const float* Wo = (const float*)d_in[7];
    const float* bo = (const float*)d_in[8];
    float* out = (float*)d_out;

    char* wsb = (char*)d_ws;
    char* ob  = (char*)d_out;
    // d_out scratch (dead before fused_out writes):
    unsigned short* vT  = (unsigned short*)ob;                    // 32 MB
    unsigned short* xb  = (unsigned short*)(ob + 33554432ull);    // 32 MB, dead after gemm_qkv
    // ws:
    unsigned short* qb  = (unsigned short*)wsb;                   // 32 MB
    unsigned short* kT  = (unsigned short*)(wsb + 33554432ull);   // 32 MB
    unsigned short* wt  = (unsigned short*)(wsb + 67108864ull);   // 2 MB
    float*          kvg = (float*)(wsb + 69206016ull);            // 1 MB
    float*          ksg = (float*)(wsb + 70254592ull);            // 16 KB

    prep_kernel<<<16640, 256, 0, stream>>>(x, Wq, Wk, Wv, Wo, xb, wt, ksg, kvg);
    gemm_qkv_kernel<<<3072, 256, 0, stream>>>(xb, wt, bq, bk, bv, qb, kT, vT, ksg);
    kv_kernel<<<512, 256, 0, stream>>>(kT, vT, kvg);
    fused_out_kernel<<<512, 256, 0, stream>>>(qb, kvg, ksg,
            wt + 3ull * 512 * 512, bo, out);
}

// Round 10
// 263.023 us; speedup vs baseline: 2.0719x; 2.0719x over previous
//
#include <hip/hip_runtime.h>
#include <hip/hip_bf16.h>

// B=8, S=4096, E=512, QKV=512, H=8, D=64, M=B*S=32768
// R13 pipeline (5 launches) = R12 + ww[8] fix in mid2 (W2 branch read only
// 32 of 64 Wo values -> OOB register garbage for m>=32):
//   prep:      x fp32 -> bf16 xb + W transposes -> wt + zero ksg/kvg
//   gemm_qkv:  q = act(x@Wq+b) row-major -> qb; k,v stored ONLY TRANSPOSED
//              kT/vT[bh][d|m][4096] bf16 (k act'd); k-blocks atomicAdd fp32
//              ksum into ksg. XCD-swizzled.
//   kv:        MFMA GEMM over s (sc=8 x 512), 2-phase dbuf, counted vmcnt(4);
//              epilogue fp32 atomicAdd into kvg[bh][m][d].
//   mid2:      blocks 0..255:  z[row,h] = 1/(q_h.ksum_h+eps); qb *= z IN PLACE
//              blocks 256..511: W2_b[h*64+d][n] = sum_m kv_bh[m][d]*Wo[h*64+m][n]
//              (fp32 kv x bf16 Wo, fp32 accum) -> bf16 w2t[b][n][k] (overlays kT)
//   gemm_out:  out = q' @ W2_b + bo  -- single 512-K GEMM (gemm_q structure),
//              B-slice per batch = per XCD (L2-resident). fp32 out -> d_out.
// ALGEBRA: out[row,n] = sum_h z[row,h] sum_d q[row,hd] sum_m kv[m,d]Wo[hm,n]
//          = (z*q) @ W2   with W2[hd,n] = sum_m kv[m,d]*Wo[h*64+m,n].
// Scratch:
//   d_out[0,32M):  vT (dead after kv), then out rows
//   d_out[32,64M): xb (dead after gemm_qkv), then out rows
//   ws: qb[0,32M) kT[32,64M)->w2t(4MB, after kv) wt[64,66M) kvg[66,67M) ksg

typedef __bf16 bf16x8 __attribute__((ext_vector_type(8)));
typedef float  f32x4  __attribute__((ext_vector_type(4)));

__device__ __forceinline__ unsigned short f2b(float f) {
    unsigned int u = __builtin_bit_cast(unsigned int, f);
    unsigned int r = (u + 0x7FFFu + ((u >> 16) & 1u)) >> 16;
    return (unsigned short)r;
}
__device__ __forceinline__ float blo(unsigned int u) {
    return __builtin_bit_cast(float, u << 16);
}
__device__ __forceinline__ float bhi(unsigned int u) {
    return __builtin_bit_cast(float, u & 0xFFFF0000u);
}
__device__ __forceinline__ unsigned int scale2(unsigned int u, float z) {
    return (unsigned int)f2b(blo(u) * z) | ((unsigned int)f2b(bhi(u) * z) << 16);
}
__device__ __forceinline__ void load_lds16(const unsigned short* g, unsigned short* l) {
    __builtin_amdgcn_global_load_lds(
        (const __attribute__((address_space(1))) void*)g,
        (__attribute__((address_space(3))) void*)l, 16, 0, 0);
}

// ---------------- prep: W transpose (blocks 0..255) + x cvt (blocks 256..) ---
__global__ void prep_kernel(const float* __restrict__ x,
                            const float* __restrict__ w0, const float* __restrict__ w1,
                            const float* __restrict__ w2, const float* __restrict__ w3,
                            unsigned short* __restrict__ xb, unsigned short* __restrict__ wt,
                            float* __restrict__ ksg, float* __restrict__ kvg) {
    __shared__ float tile[64][65];
    int t = threadIdx.x;
    if (blockIdx.x >= 256) {
        int i = (blockIdx.x - 256) * 256 + t;   // < 4194304
        float4 v = ((const float4*)x)[i];
        ushort4 o;
        o.x = f2b(v.x); o.y = f2b(v.y); o.z = f2b(v.z); o.w = f2b(v.w);
        ((ushort4*)xb)[i] = o;
        return;
    }
    int idx = blockIdx.x;
    if (idx < 16) ksg[idx * 256 + t] = 0.f;                 // zero ksum (4096 f32)
    ((float4*)kvg)[idx * 256 + t] = (float4){0.f, 0.f, 0.f, 0.f};  // zero kvg (1 MB)
    int bz = idx >> 6, by = (idx >> 3) & 7, bx = idx & 7;
    const float* src = (bz == 0) ? w0 : (bz == 1) ? w1 : (bz == 2) ? w2 : w3;
    unsigned short* dst = wt + (size_t)bz * 512 * 512;
    int rb = by * 64, cb = bx * 64;
    #pragma unroll
    for (int i = 0; i < 16; i++) {
        int c = t + i * 256; int r = c >> 6, cc = c & 63;
        tile[r][cc] = src[(rb + r) * 512 + cb + cc];
    }
    __syncthreads();
    #pragma unroll
    for (int i = 0; i < 16; i++) {
        int c = t + i * 256; int r = c >> 6, cc = c & 63;
        dst[(cb + r) * 512 + rb + cc] = f2b(tile[cc][r]);   // Wt[n][k]=W[k][n]
    }
}

// ---------------- gemm_qkv: 128x128 MFMA, q row-major / k,v transposed -------
__global__ __launch_bounds__(256, 4) void gemm_qkv_kernel(
        const unsigned short* __restrict__ xb, const unsigned short* __restrict__ wt,
        const float* __restrict__ bq, const float* __restrict__ bk, const float* __restrict__ bv,
        unsigned short* __restrict__ qb, unsigned short* __restrict__ kT,
        unsigned short* __restrict__ vT, float* __restrict__ ksg) {
    int g = blockIdx.x;
    int xcd = g & 7, slot = g >> 3;            // slot 0..383
    int mtile = xcd * 32 + slot / 12;
    int tn = slot % 12;
    int tensor = tn >> 2, ntile = tn & 3;
    const unsigned short* Bt = wt + (size_t)tensor * 512 * 512;
    const float* bias = tensor == 0 ? bq : tensor == 1 ? bk : bv;
    bool act = tensor < 2;

    __shared__ __align__(16) unsigned short sA[128 * 64];
    __shared__ __align__(16) unsigned short sB[128 * 64];
    const int tid  = threadIdx.x;
    const int wave = tid >> 6, lane = tid & 63;
    const int wm = wave >> 1, wn = wave & 1;
    const int quad = lane >> 4, l16 = lane & 15;
    const int mbase = mtile * 128, nbase = ntile * 128;
    const int rsub = lane >> 3;
    const int coff = (((lane & 7) ^ rsub) << 3);

    f32x4 acc[4][4];
    #pragma unroll
    for (int i = 0; i < 4; i++)
        #pragma unroll
        for (int j = 0; j < 4; j++) acc[i][j] = (f32x4){0.f, 0.f, 0.f, 0.f};

    for (int kb = 0; kb < 512; kb += 64) {
        #pragma unroll
        for (int t = 0; t < 4; t++) {
            int r0 = t * 32 + wave * 8;
            load_lds16(&xb[(size_t)(mbase + r0 + rsub) * 512 + kb + coff], &sA[r0 * 64]);
            load_lds16(&Bt[(size_t)(nbase + r0 + rsub) * 512 + kb + coff], &sB[r0 * 64]);
        }
        __syncthreads();
        #pragma unroll
        for (int ko = 0; ko < 64; ko += 32) {
            bf16x8 af[4], bfr[4];
            int pg = ((quad + (ko >> 3)) ^ (l16 & 7)) << 3;
            #pragma unroll
            for (int f = 0; f < 4; f++)
                af[f] = *(const bf16x8*)&sA[(wm * 64 + f * 16 + l16) * 64 + pg];
            #pragma unroll
            for (int f = 0; f < 4; f++)
                bfr[f] = *(const bf16x8*)&sB[(wn * 64 + f * 16 + l16) * 64 + pg];
            #pragma unroll
            for (int i = 0; i < 4; i++)
                #pragma unroll
                for (int j = 0; j < 4; j++)
                    acc[i][j] = __builtin_amdgcn_mfma_f32_16x16x32_bf16(af[i], bfr[j], acc[i][j], 0, 0, 0);
        }
        __syncthreads();
    }
    // epilogue. C/D layout: col = lane&15, row = quad*4+reg (m89-verified).
    if (tensor == 0) {
        #pragma unroll
        for (int i = 0; i < 4; i++)
            #pragma unroll
            for (int j = 0; j < 4; j++) {
                int gcol = nbase + wn * 64 + j * 16 + l16;
                float bv = bias[gcol];
                #pragma unroll
                for (int r = 0; r < 4; r++) {
                    int grow = mbase + wm * 64 + i * 16 + quad * 4 + r;
                    float v = acc[i][j][r] + bv;
                    v = v > 0.f ? v + 1.f : __expf(v);
                    qb[(size_t)grow * 512 + gcol] = f2b(v);
                }
            }
    } else {
        // transposed store: T[((b*8+h)*64 + d)*4096 + s], 4 consecutive s.
        unsigned short* T = (tensor == 1) ? kT : vT;
        float csum[4] = {0.f, 0.f, 0.f, 0.f};
        #pragma unroll
        for (int i = 0; i < 4; i++)
            #pragma unroll
            for (int j = 0; j < 4; j++) {
                int gcol = nbase + wn * 64 + j * 16 + l16;   // 0..511
                int h = gcol >> 6, d = gcol & 63;
                float bv = bias[gcol];
                int grow0 = mbase + wm * 64 + i * 16 + quad * 4;
                int b = grow0 >> 12, s0 = grow0 & 4095;
                ushort4 o;
                #pragma unroll
                for (int r = 0; r < 4; r++) {
                    float v = acc[i][j][r] + bv;
                    if (act) { v = v > 0.f ? v + 1.f : __expf(v); csum[j] += v; }
                    ((unsigned short*)&o)[r] = f2b(v);
                }
                *(ushort4*)&T[(((size_t)b * 8 + h) * 64 + d) * 4096 + s0] = o;
            }
        if (act) {   // tensor==1 (k): fp32 ksum accumulation, pre-bf16-rounding
            int b = mbase >> 12;
            #pragma unroll
            for (int j = 0; j < 4; j++) {
                float s = csum[j];
                s += __shfl_xor(s, 16, 64);   // quad reduce (rows quad*4+r)
                s += __shfl_xor(s, 32, 64);
                if (quad == 0) {
                    int gcol = nbase + wn * 64 + j * 16 + l16;
                    atomicAdd(&ksg[b * 512 + gcol], s);
                }
            }
        }
    }
}

// ---------------- kv: MFMA GEMM over s, 2-phase dbuf -------------------------
__global__ __launch_bounds__(256, 2) void kv_kernel(
        const unsigned short* __restrict__ kT, const unsigned short* __restrict__ vT,
        float* __restrict__ kvg) {
    int bh = blockIdx.x >> 3, sc = blockIdx.x & 7;
    const int tid = threadIdx.x;
    const int wave = tid >> 6, lane = tid & 63;
    const int wm = wave >> 1, wn = wave & 1;
    const int quad = lane >> 4, l16 = lane & 15;
    const int rsub = lane >> 3;
    const int coff = (((lane & 7) ^ rsub) << 3);
    __shared__ __align__(16) unsigned short sV[2][64 * 64];
    __shared__ __align__(16) unsigned short sK[2][64 * 64];

    f32x4 acc[2][2];
    #pragma unroll
    for (int i = 0; i < 2; i++)
        #pragma unroll
        for (int j = 0; j < 2; j++) acc[i][j] = (f32x4){0.f, 0.f, 0.f, 0.f};
    size_t base = (size_t)bh * 64 * 4096 + sc * 512;

    auto stage = [&](int kb, int buf) {
        int s0 = kb * 64;
        #pragma unroll
        for (int t = 0; t < 2; t++) {
            int r0 = t * 32 + wave * 8;
            load_lds16(&vT[base + (size_t)(r0 + rsub) * 4096 + s0 + coff], &sV[buf][r0 * 64]);
            load_lds16(&kT[base + (size_t)(r0 + rsub) * 4096 + s0 + coff], &sK[buf][r0 * 64]);
        }
    };

    stage(0, 0);                               // 4 loads in flight
    for (int kb = 0; kb < 8; kb++) {           // 8 x 64 s
        int buf = kb & 1;
        if (kb < 7) {
            stage(kb + 1, buf ^ 1);            // +4 -> 8 in flight
            asm volatile("s_waitcnt vmcnt(4)" ::: "memory");   // tile kb landed
        } else {
            asm volatile("s_waitcnt vmcnt(0)" ::: "memory");
        }
        __builtin_amdgcn_sched_barrier(0);
        __builtin_amdgcn_s_barrier();
        #pragma unroll
        for (int ko = 0; ko < 64; ko += 32) {
            bf16x8 af[2], bfr[2];
            int pg = ((quad + (ko >> 3)) ^ (l16 & 7)) << 3;
            #pragma unroll
            for (int f = 0; f < 2; f++)
                af[f] = *(const bf16x8*)&sV[buf][(wm * 32 + f * 16 + l16) * 64 + pg];
            #pragma unroll
            for (int f = 0; f < 2; f++)
                bfr[f] = *(const bf16x8*)&sK[buf][(wn * 32 + f * 16 + l16) * 64 + pg];
            #pragma unroll
            for (int i = 0; i < 2; i++)
                #pragma unroll
                for (int j = 0; j < 2; j++)
                    acc[i][j] = __builtin_amdgcn_mfma_f32_16x16x32_bf16(af[i], bfr[j], acc[i][j], 0, 0, 0);
        }
        __builtin_amdgcn_s_barrier();          // protect buf from next re-stage
        __builtin_amdgcn_sched_barrier(0);
    }
    // epilogue: accumulate fp32 partial into kvg (8 sc contenders per cell)
    float* out = kvg + (size_t)bh * 4096;
    #pragma unroll
    for (int i = 0; i < 2; i++)
        #pragma unroll
        for (int j = 0; j < 2; j++)
            #pragma unroll
            for (int r = 0; r < 4; r++) {
                int m = wm * 32 + i * 16 + quad * 4 + r;
                int d = wn * 32 + j * 16 + l16;
                atomicAdd(&out[m * 64 + d], acc[i][j][r]);
            }
}

// ---------------- mid2: z-scale qb in place + W2 build -----------------------
// blocks 0..255: per 128 rows; thread = (rowi=tid>>3, h=tid&7): dsum over 64
//   cols; z = 1/(dsum+eps); rewrite the SAME 64 q values scaled (per-thread RMW).
// blocks 256..511: (b,h,nchunk): W2[h*64+d][n] = sum_m kvg[m][d]*Wo[h*64+m][n],
//   fp32 accum, bf16 out to w2t[b][n][512] (wt-format).
__global__ __launch_bounds__(256) void mid2_kernel(
        unsigned short* __restrict__ qb, const float* __restrict__ ksg,
        const float* __restrict__ kvg, const unsigned short* __restrict__ wto,
        unsigned short* __restrict__ w2t) {
    int tid = threadIdx.x;
    if (blockIdx.x < 256) {
        int mbase = blockIdx.x * 128;
        int b = mbase >> 12;
        __shared__ float sKs[512];
        sKs[tid]       = ksg[b * 512 + tid];
        sKs[tid + 256] = ksg[b * 512 + 256 + tid];
        __syncthreads();
        int seg = tid & 7, rowi = tid >> 3;        // h = seg; 32 rows per pass
        #pragma unroll
        for (int p = 0; p < 4; p++) {
            int row = mbase + p * 32 + rowi;
            uint4* q4 = (uint4*)&qb[(size_t)row * 512 + seg * 64];
            uint4 w[2]; float dsum = 0.f;
            #pragma unroll
            for (int u4 = 0; u4 < 2; u4++) w[u4] = q4[u4];
            uint4 w2a[2]; w2a[0] = q4[2]; w2a[1] = q4[3];
            uint4 w3a[2]; w3a[0] = q4[4]; w3a[1] = q4[5];
            uint4 w4a[2]; w4a[0] = q4[6]; w4a[1] = q4[7];
            const float* ksh = &sKs[seg * 64];
            #pragma unroll
            for (int u4 = 0; u4 < 2; u4++) {
                const unsigned int* qp = (const unsigned int*)&w[u4];
                const unsigned int* qp2 = (const unsigned int*)&w2a[u4];
                const unsigned int* qp3 = (const unsigned int*)&w3a[u4];
                const unsigned int* qp4 = (const unsigned int*)&w4a[u4];
                #pragma unroll
                for (int i = 0; i < 4; i++) {
                    int c0 = u4 * 8 + i * 2;
                    dsum += blo(qp[i])  * ksh[c0]      + bhi(qp[i])  * ksh[c0 + 1];
                    dsum += blo(qp2[i]) * ksh[c0 + 16] + bhi(qp2[i]) * ksh[c0 + 17];
                    dsum += blo(qp3[i]) * ksh[c0 + 32] + bhi(qp3[i]) * ksh[c0 + 33];
                    dsum += blo(qp4[i]) * ksh[c0 + 48] + bhi(qp4[i]) * ksh[c0 + 49];
                }
            }
            float z = 1.f / (dsum + 1e-6f);
            #pragma unroll
            for (int u4 = 0; u4 < 2; u4++) {
                unsigned int* qp = (unsigned int*)&w[u4];
                unsigned int* qp2 = (unsigned int*)&w2a[u4];
                unsigned int* qp3 = (unsigned int*)&w3a[u4];
                unsigned int* qp4 = (unsigned int*)&w4a[u4];
                #pragma unroll
                for (int i = 0; i < 4; i++) {
                    qp[i] = scale2(qp[i], z);  qp2[i] = scale2(qp2[i], z);
                    qp3[i] = scale2(qp3[i], z); qp4[i] = scale2(qp4[i], z);
                }
            }
            q4[0] = w[0]; q4[1] = w[1]; q4[2] = w2a[0]; q4[3] = w2a[1];
            q4[4] = w3a[0]; q4[5] = w3a[1]; q4[6] = w4a[0]; q4[7] = w4a[1];
        }
    } else {
        int idx = blockIdx.x - 256;                // 0..255
        int b = idx >> 5, h = (idx >> 2) & 7, nc = idx & 3;
        __shared__ float kvL[4096];                // kv_bh[m][d]
        #pragma unroll
        for (int i = 0; i < 4; i++)
            ((float4*)kvL)[tid + i * 256] =
                ((const float4*)&kvg[(size_t)(b * 8 + h) * 4096])[tid + i * 256];
        __syncthreads();
        int n = nc * 128 + (tid & 127), dg = tid >> 7;   // dg: d-half
        const unsigned short* wr = &wto[(size_t)n * 512 + h * 64];
        uint4 ww[8];                               // 64 bf16 (R12 bug: was [4])
        #pragma unroll
        for (int i = 0; i < 8; i++) ww[i] = ((const uint4*)wr)[i];
        float accs[32];
        #pragma unroll
        for (int d = 0; d < 32; d++) accs[d] = 0.f;
        const unsigned int* wu = (const unsigned int*)ww;
        #pragma unroll
        for (int m = 0; m < 64; m++) {
            float wv = (m & 1) ? bhi(wu[m >> 1]) : blo(wu[m >> 1]);
            const float* kp = &kvL[m * 64 + dg * 32];   // broadcast per dg
            #pragma unroll
            for (int d = 0; d < 32; d++) accs[d] += kp[d] * wv;
        }
        unsigned short* dst = &w2t[((size_t)b * 512 + n) * 512 + h * 64 + dg * 32];
        #pragma unroll
        for (int d = 0; d < 32; d += 2)
            *(unsigned int*)&dst[d] =
                (unsigned int)f2b(accs[d]) | ((unsigned int)f2b(accs[d + 1]) << 16);
    }
}

// ---------------- gemm_out: out = q' @ W2_b + bo -----------------------------
// grid: 1024 1-D, XCD-swizzled; mtile>>5 = b = xcd -> per-XCD B-slice (512KB,
// L2-resident). Identical structure to gemm_q.
__global__ __launch_bounds__(256, 4) void gemm_out_kernel(
        const unsigned short* __restrict__ qb, const unsigned short* __restrict__ w2t,
        const float* __restrict__ bo, float* __restrict__ out) {
    int g = blockIdx.x;
    int xcd = g & 7, slot = g >> 3;            // slot 0..127
    int mtile = xcd * 32 + (slot >> 2);
    int ntile = slot & 3;
    const int b = mtile >> 5;
    const unsigned short* Bt = w2t + (size_t)b * 512 * 512;

    __shared__ __align__(16) unsigned short sA[128 * 64];
    __shared__ __align__(16) unsigned short sB[128 * 64];
    const int tid  = threadIdx.x;
    const int wave = tid >> 6, lane = tid & 63;
    const int wm = wave >> 1, wn = wave & 1;
    const int quad = lane >> 4, l16 = lane & 15;
    const int mbase = mtile * 128, nbase = ntile * 128;
    const int rsub = lane >> 3;
    const int coff = (((lane & 7) ^ rsub) << 3);

    f32x4 acc[4][4];
    #pragma unroll
    for (int i = 0; i < 4; i++)
        #pragma unroll
        for (int j = 0; j < 4; j++) acc[i][j] = (f32x4){0.f, 0.f, 0.f, 0.f};

    for (int kb = 0; kb < 512; kb += 64) {
        #pragma unroll
        for (int t = 0; t < 4; t++) {
            int r0 = t * 32 + wave * 8;
            load_lds16(&qb[(size_t)(mbase + r0 + rsub) * 512 + kb + coff], &sA[r0 * 64]);
            load_lds16(&Bt[(size_t)(nbase + r0 + rsub) * 512 + kb + coff], &sB[r0 * 64]);
        }
        __syncthreads();
        #pragma unroll
        for (int ko = 0; ko < 64; ko += 32) {
            bf16x8 af[4], bfr[4];
            int pg = ((quad + (ko >> 3)) ^ (l16 & 7)) << 3;
            #pragma unroll
            for (int f = 0; f < 4; f++)
                af[f] = *(const bf16x8*)&sA[(wm * 64 + f * 16 + l16) * 64 + pg];
            #pragma unroll
            for (int f = 0; f < 4; f++)
                bfr[f] = *(const bf16x8*)&sB[(wn * 64 + f * 16 + l16) * 64 + pg];
            #pragma unroll
            for (int i = 0; i < 4; i++)
                #pragma unroll
                for (int j = 0; j < 4; j++)
                    acc[i][j] = __builtin_amdgcn_mfma_f32_16x16x32_bf16(af[i], bfr[j], acc[i][j], 0, 0, 0);
        }
        __syncthreads();
    }
    #pragma unroll
    for (int i = 0; i < 4; i++)
        #pragma unroll
        for (int j = 0; j < 4; j++) {
            int gcol = nbase + wn * 64 + j * 16 + l16;
            float bvv = bo[gcol];
            #pragma unroll
            for (int r = 0; r < 4; r++) {
                int grow = mbase + wm * 64 + i * 16 + quad * 4 + r;
                out[(size_t)grow * 512 + gcol] = acc[i][j][r] + bvv;
            }
        }
}

// ---------------- launch -----------------------------------------------------
extern "C" void kernel_launch(void* const* d_in, const int* in_sizes, int n_in,
                              void* d_out, int out_size, void* d_ws, size_t ws_size,
                              hipStream_t stream) {
    const float* x  = (const float*)d_in[0];
    const float* Wq = (const float*)d_in[1];
    const float* bq = (const float*)d_in[2];
    const float* Wk = (const float*)d_in[3];
    const float* bk = (const float*)d_in[4];
    const float* Wv = (const float*)d_in[5];
    const float* bv = (const float*)d_in[6];
    const float* Wo = (const float*)d_in[7];
    const float* bo = (const float*)d_in[8];
    float* out = (float*)d_out;

    char* wsb = (char*)d_ws;
    char* ob  = (char*)d_out;
    // d_out scratch (dead before gemm_out writes):
    unsigned short* vT  = (unsigned short*)ob;                    // 32 MB
    unsigned short* xb  = (unsigned short*)(ob + 33554432ull);    // 32 MB
    // ws:
    unsigned short* qb  = (unsigned short*)wsb;                   // 32 MB
    unsigned short* kT  = (unsigned short*)(wsb + 33554432ull);   // 32 MB (dead after kv)
    unsigned short* w2t = kT;                                     // 4 MB, overlays kT
    unsigned short* wt  = (unsigned short*)(wsb + 67108864ull);   // 2 MB
    float*          kvg = (float*)(wsb + 69206016ull);            // 1 MB
    float*          ksg = (float*)(wsb + 70254592ull);            // 16 KB

    prep_kernel<<<16640, 256, 0, stream>>>(x, Wq, Wk, Wv, Wo, xb, wt, ksg, kvg);
    gemm_qkv_kernel<<<3072, 256, 0, stream>>>(xb, wt, bq, bk, bv, qb, kT, vT, ksg);
    kv_kernel<<<512, 256, 0, stream>>>(kT, vT, kvg);
    mid2_kernel<<<512, 256, 0, stream>>>(qb, ksg, kvg,
            wt + 3ull * 512 * 512, w2t);
    gemm_out_kernel<<<1024, 256, 0, stream>>>(qb, w2t, bo, out);
}